// Round 31
// baseline (608.622 us; speedup 1.0000x reference)
//
#include <hip/hip_runtime.h>
#include <hip/hip_fp16.h>

#define DMv 384
#define DEv 64

typedef __attribute__((ext_vector_type(8))) __bf16 bf16x8;
typedef __attribute__((ext_vector_type(4))) float f32x4;
typedef _Float16 hf16x2 __attribute__((ext_vector_type(2)));

// ---------- bf16 helpers (raw ushort storage) ----------
__device__ __forceinline__ float bf_lo(unsigned u){ return __uint_as_float(u << 16); }
__device__ __forceinline__ float bf_hi(unsigned u){ return __uint_as_float(u & 0xffff0000u); }
__device__ __forceinline__ unsigned short f2bf(float f){
  unsigned u = __float_as_uint(f);
  unsigned r = (u + 0x7fffu + ((u >> 16) & 1u)) >> 16;
  return (unsigned short)r;
}
__device__ __forceinline__ float bf2f(unsigned short s){ return __uint_as_float(((unsigned)s) << 16); }

// ---------- f16 helpers ----------
__device__ __forceinline__ unsigned packh2(float a, float b){
  unsigned short ha = __half_as_ushort(__float2half(a));
  unsigned short hb = __half_as_ushort(__float2half(b));
  return (unsigned)ha | ((unsigned)hb << 16);
}
__device__ __forceinline__ float h_lo(unsigned u){ return __half2float(__ushort_as_half((unsigned short)(u & 0xffffu))); }
__device__ __forceinline__ float h_hi(unsigned u){ return __half2float(__ushort_as_half((unsigned short)(u >> 16))); }
__device__ __forceinline__ hf16x2 u2h(unsigned u){ union { unsigned u; hf16x2 h; } x; x.u = u; return x.h; }
// dot2: c += a.x*b.x + a.y*b.y  (v_dot2_f32_f16)
__device__ __forceinline__ float dot2(unsigned a, unsigned b, float c){
  return __builtin_amdgcn_fdot2(u2h(a), u2h(b), c, false);
}

// column permutation for W2P: lane l owns cols 6l..6l+5; col-pair cp=3l+m stored at l+64m
__device__ __forceinline__ int phi_col(int c){
  int cp = c >> 1, l = cp / 3, m = cp - 3*l;
  return ((l + (m << 6)) << 1) | (c & 1);
}

// ---------- atom embedding: hbf = bf16(lut[x] * sqrt(384)); also zero cnt ----------
__global__ void embed_k(const int* __restrict__ x, const float* __restrict__ lut,
                        unsigned short* __restrict__ hbf, int* __restrict__ cnt) {
  int n = blockIdx.x, c = threadIdx.x;
  if (c == 0) cnt[n] = 0;
  hbf[(size_t)n*DMv + c] = f2bf(lut[(size_t)x[n]*DMv + c] * 19.595917942265423f);
}

// ---------- W2 = We0 @ We  (f32 [2][48][384], rows 41..47 zero), bias2 = be0 @ We ----------
__global__ void w2_k(const float* __restrict__ We0, const float* __restrict__ be0,
                     const float* __restrict__ We, float* __restrict__ W2,
                     float* __restrict__ bias2) {
  int k = blockIdx.x;         // 0..48
  int l = blockIdx.y;
  int j = threadIdx.x;        // 0..383
  const float* Wel = We + (size_t)l*DEv*DMv;
  if (k == 48) {
    float s = 0.f;
    for (int c = 0; c < DEv; ++c) s = fmaf(be0[c], Wel[c*DMv + j], s);
    bias2[l*DMv + j] = s;
    return;
  }
  float s = 0.f;
  if (k < 41) {
    for (int c = 0; c < DEv; ++c) s = fmaf(We0[k*DEv + c], Wel[c*DMv + j], s);
  }
  W2[((size_t)l*48 + k)*DMv + j] = s;
}

// ---------- W2P: f16 row-pair packed, col-permuted  [2][24][384] uints ----------
__global__ void w2p_k(const float* __restrict__ W2, unsigned* __restrict__ W2P) {
  int p = blockIdx.x;         // 0..23 (row pair)
  int l = blockIdx.y;
  int c = threadIdx.x;        // 0..383
  const float* base = W2 + (size_t)l*48*DMv;
  float a = base[(2*p)*DMv + c];
  float b = base[(2*p+1)*DMv + c];
  W2P[((size_t)l*24 + p)*DMv + phi_col(c)] = packh2(a, b);
}

// ---------- WcatT bf16 [2][1152][384] via LDS 64x64 tile transpose (coalesced both sides) ----------
__global__ void wcat_k(const float* __restrict__ Wl, const float* __restrict__ Wr,
                       const float* __restrict__ Wres, unsigned short* __restrict__ WcatT) {
  __shared__ float tile[64][65];
  int nb = blockIdx.x;   // 0..17 (n tile)
  int kb = blockIdx.y;   // 0..5  (k tile)
  int l  = blockIdx.z;
  int n0 = nb*64;
  const float* src;
  int nnb;
  if (n0 < 384)      { src = Wl   + (size_t)l*DMv*DMv; nnb = n0; }
  else if (n0 < 768) { src = Wr   + (size_t)l*DMv*DMv; nnb = n0 - 384; }
  else               { src = Wres + (size_t)l*DMv*DMv; nnb = n0 - 768; }
  int tid = threadIdx.x;
  // read: coalesced rows of src (k-major)
  #pragma unroll
  for (int it = 0; it < 16; ++it) {
    int idx = it*256 + tid;
    int kl = idx >> 6, nl = idx & 63;
    tile[kl][nl] = src[(size_t)(kb*64 + kl)*DMv + nnb + nl];
  }
  __syncthreads();
  // write: coalesced rows of WcatT (n-major)
  #pragma unroll
  for (int it = 0; it < 16; ++it) {
    int idx = it*256 + tid;
    int nl = idx >> 6, kl = idx & 63;
    WcatT[((size_t)l*1152 + n0 + nl)*DMv + kb*64 + kl] = f2bf(tile[kl][nl]);
  }
}

// ---------- per-edge 8-value gaussian basis window (start mult of 4), f16-pair packed ----------
__global__ void bas8_k(const float* __restrict__ edge_attr,
                       uint4* __restrict__ bas8, int* __restrict__ ofs, int Ecnt) {
  int e = blockIdx.x*256 + threadIdx.x;
  if (e >= Ecnt) return;
  float d = edge_attr[e];
  int kc = (int)(d*5.0f + 0.5f);
  int s = (kc - 2) & ~3;
  if (s < 0) s = 0;
  float v[8];
  #pragma unroll
  for (int i = 0; i < 8; ++i) {
    float df = (d - 0.2f*(float)(s+i)) * 5.0f;
    v[i] = __expf(-(df*df)) * (1.0f/1.12f);
  }
  uint4 u;
  u.x = packh2(v[0], v[1]);
  u.y = packh2(v[2], v[3]);
  u.z = packh2(v[4], v[5]);
  u.w = packh2(v[6], v[7]);
  bas8[e] = u;
  ofs[e] = s;
}

// ---------- CSR build (count also zeroes fillA + sort bins) ----------
__global__ void count_k(const int* __restrict__ tgt, int* __restrict__ cnt,
                        int* __restrict__ fillA, int* __restrict__ hist,
                        int* __restrict__ fillB, int Ecnt, int Nn) {
  int e = blockIdx.x*256 + threadIdx.x;
  if (e < Nn) fillA[e] = 0;
  if (e < 512) { hist[e] = 0; fillB[e] = 0; }
  if (e < Ecnt) atomicAdd(&cnt[tgt[e]], 1);
}
// degree histogram: LDS-aggregated (hot bins hit LDS atomics, not global)
__global__ void dhist_k(const int* __restrict__ cnt, int* __restrict__ hist, int Nn) {
  __shared__ int lh[512];
  int tid = threadIdx.x;
  lh[tid] = 0; lh[tid + 256] = 0;
  __syncthreads();
  int t = blockIdx.x*256 + tid;
  if (t < Nn) { int b = cnt[t]; if (b > 511) b = 511; atomicAdd(&lh[b], 1); }
  __syncthreads();
  int v0 = lh[tid], v1 = lh[tid + 256];
  if (v0) atomicAdd(&hist[tid], v0);
  if (v1) atomicAdd(&hist[tid + 256], v1);
}
// descending-degree exclusive bin offsets (single block, 512 threads)
__global__ void dscan_k(const int* __restrict__ hist, int* __restrict__ binofs) {
  __shared__ int tmp[512];
  int tid = threadIdx.x;
  int v = hist[511 - tid];
  tmp[tid] = v; __syncthreads();
  for (int off = 1; off < 512; off <<= 1) {
    int xv = (tid >= off) ? tmp[tid-off] : 0;
    __syncthreads();
    tmp[tid] += xv;
    __syncthreads();
  }
  binofs[511 - tid] = tmp[tid] - v;
}
// scatter nodes into perm, largest degree first: LDS local rank + per-block chunk claim
__global__ void dfill_k(const int* __restrict__ cnt, const int* __restrict__ binofs,
                        int* __restrict__ fillB, int* __restrict__ perm, int Nn) {
  __shared__ int lh[512];     // per-block bin counts (then reused as ranks)
  __shared__ int lbase[512];  // per-block global chunk base per bin
  int tid = threadIdx.x;
  lh[tid] = 0; lh[tid + 256] = 0;
  __syncthreads();
  int t = blockIdx.x*256 + tid;
  int b = -1, lr = 0;
  if (t < Nn) {
    b = cnt[t]; if (b > 511) b = 511;
    lr = atomicAdd(&lh[b], 1);          // local rank within (block, bin)
  }
  __syncthreads();
  int c0 = lh[tid], c1 = lh[tid + 256];
  if (c0) lbase[tid]       = atomicAdd(&fillB[tid], c0);
  if (c1) lbase[tid + 256] = atomicAdd(&fillB[tid + 256], c1);
  __syncthreads();
  if (b >= 0) perm[binofs[b] + lbase[b] + lr] = t;
}
__global__ void scan1_k(const int* __restrict__ cnt, int* __restrict__ rowptr,
                        int* __restrict__ bsum, int n) {
  __shared__ int tmp[256];
  int tid = threadIdx.x, i = blockIdx.x*256 + tid;
  int v = (i < n) ? cnt[i] : 0;
  tmp[tid] = v; __syncthreads();
  for (int off = 1; off < 256; off <<= 1) {
    int xv = (tid >= off) ? tmp[tid-off] : 0;
    __syncthreads();
    tmp[tid] += xv;
    __syncthreads();
  }
  if (i < n) rowptr[i] = tmp[tid] - v;
  if (tid == 255) bsum[blockIdx.x] = tmp[255];
}
__global__ void scan2_k(const int* __restrict__ bsum, int* __restrict__ bsumx, int nb) {
  __shared__ int tmp[256];
  int tid = threadIdx.x;
  int v = (tid < nb) ? bsum[tid] : 0;
  tmp[tid] = v; __syncthreads();
  for (int off = 1; off < 256; off <<= 1) {
    int xv = (tid >= off) ? tmp[tid-off] : 0;
    __syncthreads();
    tmp[tid] += xv;
    __syncthreads();
  }
  bsumx[tid] = tmp[tid] - v;
}
__global__ void scan3_k(int* __restrict__ rowptr, const int* __restrict__ bsumx,
                        int n, int total) {
  int i = blockIdx.x*256 + threadIdx.x;
  if (i < n) rowptr[i] += bsumx[blockIdx.x];
  if (i == 0) rowptr[n] = total;
}
// fill CSR slots with edge records (CSR-ordered copies for streaming access)
__global__ void fill_k(const int* __restrict__ srcs, const int* __restrict__ tgt,
                       const int* __restrict__ rowptr, int* __restrict__ fill,
                       const uint4* __restrict__ bas8, const int* __restrict__ ofs,
                       int* __restrict__ srcc,
                       uint4* __restrict__ bas8c, int* __restrict__ ofsc, int Ecnt) {
  int e = blockIdx.x*256 + threadIdx.x;
  if (e >= Ecnt) return;
  int t = tgt[e];
  int pos = rowptr[t] + atomicAdd(&fill[t], 1);
  srcc[pos] = srcs[e];
  ofsc[pos] = ofs[e];
  bas8c[pos] = bas8[e];
}

// ---------- per-node mean basis: mbpk[N][24] f16-pair packed uints; also zero bnsum ----------
__global__ void mb_k(const uint4* __restrict__ bas8c, const int* __restrict__ ofsc,
                     const int* __restrict__ rowptr,
                     unsigned* __restrict__ mbpk, float* __restrict__ bnsum, int Nn) {
  __shared__ float mbS[4][48];
  int tid = threadIdx.x, lane = tid & 63, wv = tid >> 6;
  int gid = blockIdx.x*256 + tid;
  if (gid < 2*DMv) bnsum[gid] = 0.f;
  int t = blockIdx.x*4 + wv;
  if (t >= Nn) return;
  if (lane < 48) mbS[wv][lane] = 0.f;
  asm volatile("s_waitcnt lgkmcnt(0)" ::: "memory");
  int rp = rowptr[t], deg = rowptr[t+1] - rp;
  for (int base = 0; base < deg; base += 64) {
    int i = base + lane;
    if (i < deg) {
      uint4 bu = bas8c[rp + i];
      int s = ofsc[rp + i];
      atomicAdd(&mbS[wv][s+0], h_lo(bu.x));
      atomicAdd(&mbS[wv][s+1], h_hi(bu.x));
      atomicAdd(&mbS[wv][s+2], h_lo(bu.y));
      atomicAdd(&mbS[wv][s+3], h_hi(bu.y));
      atomicAdd(&mbS[wv][s+4], h_lo(bu.z));
      atomicAdd(&mbS[wv][s+5], h_hi(bu.z));
      atomicAdd(&mbS[wv][s+6], h_lo(bu.w));
      atomicAdd(&mbS[wv][s+7], h_hi(bu.w));
    }
  }
  asm volatile("s_waitcnt lgkmcnt(0)" ::: "memory");
  if (lane < 24) {
    float inv = (deg > 0) ? 1.0f / (float)deg : 0.f;
    float a = (2*lane   < 44) ? mbS[wv][2*lane  ] * inv : 0.f;
    float b = (2*lane+1 < 44) ? mbS[wv][2*lane+1] * inv : 0.f;
    mbpk[(size_t)t*24 + lane] = packh2(a, b);
  }
}

// ---------- bf16 MFMA GEMM: [M x 384] @ [384 x 1152] -> xlh | xrh | hresh (all f16 packed) ----------
// 1D grid, XCD-bijective swizzle: the 9 N-tile blocks sharing an A-tile stay on one XCD -> A is L2-hit.
__global__ __launch_bounds__(256) void mfma_cat_k(
    const unsigned short* __restrict__ Abf,
    const unsigned short* __restrict__ Bt,
    const float* __restrict__ b0, const float* __restrict__ b1, const float* __restrict__ b2,
    unsigned* __restrict__ C0h, unsigned* __restrict__ C1h, unsigned* __restrict__ C2h, int M) {
  __shared__ __align__(16) char smem[64*132*4];   // 33.8 KB: staging (32KB) / C epilogue
  unsigned short* As = (unsigned short*)smem;
  unsigned short* Bs = (unsigned short*)(smem + 16384);
  float* Cs = (float*)smem;
  int tid = threadIdx.x;
  int lane = tid & 63, wv = tid >> 6;
  int wr = wv >> 1, wc = wv & 1;
  // bijective XCD chunk swizzle (nwg not necessarily %8==0)
  int nwg = gridDim.x;
  int q = nwg >> 3, r = nwg & 7;
  int xcd = blockIdx.x & 7, j = blockIdx.x >> 3;
  int base = (xcd < r) ? xcd*(q+1) : r*(q+1) + (xcd - r)*q;
  int wg = base + j;
  int bn = (wg % 9) * 128;
  int bm = (wg / 9) * 128;
  int srow = tid >> 3;
  int scol = (tid & 7) * 8;
  f32x4 acc[4][4] = {};
  uint4 av[4], bv[4];
  #pragma unroll
  for (int c = 0; c < 4; ++c) {
    int gr = bm + c*32 + srow; if (gr >= M) gr = M - 1;
    av[c] = *(const uint4*)(Abf + (size_t)gr*DMv + scol);
    bv[c] = *(const uint4*)(Bt + (size_t)(bn + c*32 + srow)*DMv + scol);
  }
  #pragma unroll
  for (int kt = 0; kt < 6; ++kt) {
    __syncthreads();
    #pragma unroll
    for (int c = 0; c < 4; ++c) {
      int r2 = c*32 + srow;
      int byteA = r2*128 + scol*2;
      byteA ^= ((byteA >> 9) & 1) << 5;
      *(uint4*)((char*)As + byteA) = av[c];
      *(uint4*)((char*)Bs + byteA) = bv[c];
    }
    __syncthreads();
    if (kt < 5) {
      int k0 = (kt+1) * 64;
      #pragma unroll
      for (int c = 0; c < 4; ++c) {
        int gr = bm + c*32 + srow; if (gr >= M) gr = M - 1;
        av[c] = *(const uint4*)(Abf + (size_t)gr*DMv + k0 + scol);
        bv[c] = *(const uint4*)(Bt + (size_t)(bn + c*32 + srow)*DMv + k0 + scol);
      }
    }
    #pragma unroll
    for (int ks = 0; ks < 2; ++ks) {
      bf16x8 af[4], bfv[4];
      #pragma unroll
      for (int m = 0; m < 4; ++m) {
        int r2 = wr*64 + m*16 + (lane & 15);
        int byte = r2*128 + ks*64 + ((lane >> 4)*16);
        byte ^= ((byte >> 9) & 1) << 5;
        af[m] = *(const bf16x8*)((const char*)As + byte);
      }
      #pragma unroll
      for (int n = 0; n < 4; ++n) {
        int r2 = wc*64 + n*16 + (lane & 15);
        int byte = r2*128 + ks*64 + ((lane >> 4)*16);
        byte ^= ((byte >> 9) & 1) << 5;
        bfv[n] = *(const bf16x8*)((const char*)Bs + byte);
      }
      #pragma unroll
      for (int m = 0; m < 4; ++m)
        #pragma unroll
        for (int n = 0; n < 4; ++n)
          acc[m][n] = __builtin_amdgcn_mfma_f32_16x16x32_bf16(af[m], bfv[n], acc[m][n], 0, 0, 0);
    }
  }
  int seg = bn / 384;
  const float* bias = (seg == 0) ? b0 : (seg == 1) ? b1 : b2;
  unsigned* C = (seg == 0) ? C0h : (seg == 1) ? C1h : C2h;
  int cbase = bn - seg*384;
  // epilogue: stage 64x128 halves in LDS (pad 132); all segs packed f16 uint2 stores
  #pragma unroll
  for (int half = 0; half < 2; ++half) {
    __syncthreads();
    if (wr == half) {
      #pragma unroll
      for (int m = 0; m < 4; ++m) {
        int rl = m*16 + ((lane >> 4)*4);
        #pragma unroll
        for (int n = 0; n < 4; ++n) {
          int cl = wc*64 + n*16 + (lane & 15);
          #pragma unroll
          for (int q2 = 0; q2 < 4; ++q2)
            Cs[(rl+q2)*132 + cl] = acc[m][n][q2];
        }
      }
    }
    __syncthreads();
    #pragma unroll
    for (int rep = 0; rep < 8; ++rep) {
      int rl = rep*8 + (tid >> 5);
      int c4 = (tid & 31) * 4;
      int gr = bm + half*64 + rl;
      if (gr < M) {
        float4 v = *(const float4*)&Cs[rl*132 + c4];
        float4 bv4 = *(const float4*)(bias + cbase + c4);
        v.x += bv4.x; v.y += bv4.y; v.z += bv4.z; v.w += bv4.w;
        uint2 pk;
        pk.x = packh2(v.x, v.y);
        pk.y = packh2(v.z, v.w);
        *(uint2*)(C + (size_t)gr*192 + ((cbase + c4) >> 1)) = pk;
      }
    }
  }
}

// ---------- fused phase: 1 node/wave via degree-sorted perm; 21-pair W2P (32.2 KB -> 5 blocks/CU) ----------
// W2 rows 42..47 are exact zeros (basis has 41 rows): pairs 21..23 never contribute.
__global__ __launch_bounds__(256) void fused_agg_k(
    const unsigned* __restrict__ xlh, const unsigned* __restrict__ xrh,
    const unsigned* __restrict__ hresh,
    const uint4* __restrict__ bas8c, const int* __restrict__ ofsc,
    const int* __restrict__ srcc, const int* __restrict__ rowptr,
    const unsigned* __restrict__ mbpk, const int* __restrict__ perm,
    const unsigned* __restrict__ W2Pg, const float* __restrict__ bias2_l,
    const float* __restrict__ att_l,
    const float* __restrict__ ln_g, const float* __restrict__ ln_b,
    unsigned short* __restrict__ hbf, int Nn) {
  __shared__ unsigned W2P[21 * DMv];          // f16-pair packed, col-permuted, 32.2 KB
  int tid = threadIdx.x;
  for (int i = tid; i < 21*DMv; i += 256) W2P[i] = W2Pg[i];
  __syncthreads();
  int lane = tid & 63, wv = tid >> 6;
  int j0 = lane * 6;
  float att_j[6], b2[6], lg[6], lb[6];
  #pragma unroll
  for (int jj = 0; jj < 6; ++jj) {
    att_j[jj] = att_l[j0 + jj];
    b2[jj]    = bias2_l[j0 + jj];
    lg[jj]    = ln_g[j0 + jj];
    lb[jj]    = ln_b[j0 + jj];
  }
  int idx = blockIdx.x*4 + wv;                // 1 node per wave
  if (idx >= Nn) return;
  int t = perm[idx];                          // degree-descending order
  {
    int rp = rowptr[t], deg = rowptr[t+1] - rp;
    const unsigned* yp = xrh + (size_t)t*192 + lane*3;
    unsigned y0 = yp[0], y1 = yp[1], y2 = yp[2];
    float xrr[6] = {h_lo(y0), h_hi(y0), h_lo(y1), h_hi(y1), h_lo(y2), h_hi(y2)};
    float xrb[6];
    #pragma unroll
    for (int jj = 0; jj < 6; ++jj) xrb[jj] = xrr[jj] + b2[jj];
    float S = 0.f;
    float acc[6] = {0.f,0.f,0.f,0.f,0.f,0.f};
    // edge records in registers (lane 0..7), double-buffered
    int r_src = 0, r_ofs = 0; uint4 r_bu = {0,0,0,0};
    if (deg > 0 && lane < 8) {
      int idx2 = lane; if (idx2 >= deg) idx2 = deg - 1;
      int p = rp + idx2;
      r_src = srcc[p]; r_bu = bas8c[p]; r_ofs = ofsc[p];
    }
    for (int base = 0; base < deg; base += 8) {
      int nb = deg - base; if (nb > 8) nb = 8;
      // prefetch next batch records into regs (independent, overlapped)
      int n_src = 0, n_ofs = 0; uint4 n_bu = {0,0,0,0};
      if (base + 8 < deg && lane < 8) {
        int idx2 = base + 8 + lane; if (idx2 >= deg) idx2 = deg - 1;
        int p = rp + idx2;
        n_src = srcc[p]; n_bu = bas8c[p]; n_ofs = ofsc[p];
      }
      // batch-wide gather: 24 independent 4B loads in flight (12B/lane, f16-packed)
      float xls[8][6];
      #pragma unroll
      for (int s = 0; s < 8; ++s) {
        int sr = __shfl(r_src, s);
        const unsigned* xp = xlh + (size_t)sr*192 + lane*3;
        unsigned u0 = xp[0], u1 = xp[1], u2 = xp[2];
        xls[s][0]=h_lo(u0); xls[s][1]=h_hi(u0); xls[s][2]=h_lo(u1);
        xls[s][3]=h_hi(u1); xls[s][4]=h_lo(u2); xls[s][5]=h_hi(u2);
      }
      #pragma unroll
      for (int s = 0; s < 8; ++s) {
        if (s >= nb) break;
        int p0 = __shfl(r_ofs, s) >> 1;       // wave-uniform pair base (even, <= 18)
        unsigned bq0 = __shfl((int)r_bu.x, s);
        unsigned bq1 = __shfl((int)r_bu.y, s);
        unsigned bq2 = __shfl((int)r_bu.z, s);
        unsigned bq3 = __shfl((int)r_bu.w, s);
        int p3 = p0 + 3;
        if (p3 > 20) { p3 = 0; bq3 = 0u; }    // pair 21 = zero rows: 0-weight exact
        float m6[6];
        #pragma unroll
        for (int jj = 0; jj < 6; ++jj) m6[jj] = xls[s][jj] + xrb[jj];
        const uint2* row0 = (const uint2*)(W2P + (p0 + 0)*DMv);
        const uint2* row1 = (const uint2*)(W2P + (p0 + 1)*DMv);
        const uint2* row2 = (const uint2*)(W2P + (p0 + 2)*DMv);
        const uint2* row3 = (const uint2*)(W2P + p3*DMv);
        #pragma unroll
        for (int m = 0; m < 3; ++m) {
          uint2 w0 = row0[lane + (m << 6)];
          uint2 w1 = row1[lane + (m << 6)];
          uint2 w2 = row2[lane + (m << 6)];
          uint2 w3 = row3[lane + (m << 6)];
          m6[2*m]   = dot2(w0.x, bq0, m6[2*m]);
          m6[2*m+1] = dot2(w0.y, bq0, m6[2*m+1]);
          m6[2*m]   = dot2(w1.x, bq1, m6[2*m]);
          m6[2*m+1] = dot2(w1.y, bq1, m6[2*m+1]);
          m6[2*m]   = dot2(w2.x, bq2, m6[2*m]);
          m6[2*m+1] = dot2(w2.y, bq2, m6[2*m+1]);
          m6[2*m]   = dot2(w3.x, bq3, m6[2*m]);
          m6[2*m+1] = dot2(w3.y, bq3, m6[2*m+1]);
        }
        float part = 0.f;
        #pragma unroll
        for (int jj = 0; jj < 6; ++jj) {
          float vl = (m6[jj] > 0.f) ? m6[jj] : 0.2f*m6[jj];
          part = fmaf(vl, att_j[jj], part);
        }
        part += __shfl_xor(part, 1);
        part += __shfl_xor(part, 2);
        part += __shfl_xor(part, 4);
        float w = __expf(part);               // this lane's head weight for edge s
        S += w;
        #pragma unroll
        for (int jj = 0; jj < 6; ++jj) acc[jj] = fmaf(w, xls[s][jj], acc[jj]);
      }
      r_src = n_src; r_bu = n_bu; r_ofs = n_ofs;
    }
    // self-loop: eproj = mb @ W2 (pairs 0..20; pairs 21..23 are zero rows)
    {
      const unsigned* xp = xlh + (size_t)t*192 + lane*3;
      unsigned u0 = xp[0], u1 = xp[1], u2 = xp[2];
      float xlt[6] = {h_lo(u0), h_hi(u0), h_lo(u1), h_hi(u1), h_lo(u2), h_hi(u2)};
      float m6[6];
      #pragma unroll
      for (int jj = 0; jj < 6; ++jj)
        m6[jj] = xlt[jj] + ((deg > 0) ? xrb[jj] : xrr[jj]);
      const uint4* mbp4 = (const uint4*)(mbpk + (size_t)t*24);
      #pragma unroll
      for (int w6 = 0; w6 < 5; ++w6) {
        uint4 bu = mbp4[w6];
        unsigned bq[4] = {bu.x, bu.y, bu.z, bu.w};
        #pragma unroll
        for (int q = 0; q < 4; ++q) {
          const uint2* rowq = (const uint2*)(W2P + (w6*4 + q)*DMv);
          #pragma unroll
          for (int m = 0; m < 3; ++m) {
            uint2 wv2 = rowq[lane + (m << 6)];
            m6[2*m]   = dot2(wv2.x, bq[q], m6[2*m]);
            m6[2*m+1] = dot2(wv2.y, bq[q], m6[2*m+1]);
          }
        }
      }
      {
        unsigned bq20 = mbpk[(size_t)t*24 + 20];
        const uint2* rowq = (const uint2*)(W2P + 20*DMv);
        #pragma unroll
        for (int m = 0; m < 3; ++m) {
          uint2 wv2 = rowq[lane + (m << 6)];
          m6[2*m]   = dot2(wv2.x, bq20, m6[2*m]);
          m6[2*m+1] = dot2(wv2.y, bq20, m6[2*m+1]);
        }
      }
      float part = 0.f;
      #pragma unroll
      for (int jj = 0; jj < 6; ++jj) {
        float vl = (m6[jj] > 0.f) ? m6[jj] : 0.2f*m6[jj];
        part = fmaf(vl, att_j[jj], part);
      }
      part += __shfl_xor(part, 1);
      part += __shfl_xor(part, 2);
      part += __shfl_xor(part, 4);
      float w = __expf(part);
      S += w;
      #pragma unroll
      for (int jj = 0; jj < 6; ++jj) acc[jj] = fmaf(w, xlt[jj], acc[jj]);
    }
    // finalize: /S, residual (f16 hres), LayerNorm, write bf16
    float inv = 1.0f / (S + 1e-16f);
    const unsigned* hq = hresh + (size_t)t*192 + lane*3;
    unsigned hh0 = hq[0], hh1 = hq[1], hh2 = hq[2];
    float hr[6] = {h_lo(hh0), h_hi(hh0), h_lo(hh1), h_hi(hh1), h_lo(hh2), h_hi(hh2)};
    float outv[6]; float s1 = 0.f, s2 = 0.f;
    #pragma unroll
    for (int jj = 0; jj < 6; ++jj) {
      float o = fmaf(acc[jj], inv, hr[jj]);
      outv[jj] = o; s1 += o; s2 += o*o;
    }
    #pragma unroll
    for (int m = 1; m < 64; m <<= 1) {
      s1 += __shfl_xor(s1, m);
      s2 += __shfl_xor(s2, m);
    }
    float mu  = s1 * (1.0f/384.0f);
    float var = s2 * (1.0f/384.0f) - mu*mu;
    float rs  = rsqrtf(var + 1e-5f);
    float o0 = (outv[0]-mu)*rs*lg[0] + lb[0];
    float o1 = (outv[1]-mu)*rs*lg[1] + lb[1];
    float o2 = (outv[2]-mu)*rs*lg[2] + lb[2];
    float o3 = (outv[3]-mu)*rs*lg[3] + lb[3];
    float o4 = (outv[4]-mu)*rs*lg[4] + lb[4];
    float o5 = (outv[5]-mu)*rs*lg[5] + lb[5];
    unsigned* hp = (unsigned*)(hbf + (size_t)t*DMv + j0);
    hp[0] = (unsigned)f2bf(o0) | ((unsigned)f2bf(o1) << 16);
    hp[1] = (unsigned)f2bf(o2) | ((unsigned)f2bf(o3) << 16);
    hp[2] = (unsigned)f2bf(o4) | ((unsigned)f2bf(o5) << 16);
  }
}

// ---------- BatchNorm (training-mode batch stats) on bf16 h ----------
__global__ void bn_reduce_k(const unsigned short* __restrict__ hbf, float* __restrict__ sums, int Nn) {
  int c = threadIdx.x;
  float s = 0.f, s2 = 0.f;
  for (int r = blockIdx.x; r < Nn; r += gridDim.x) {
    float v = bf2f(hbf[(size_t)r*DMv + c]);
    s += v; s2 += v*v;
  }
  atomicAdd(&sums[c], s);
  atomicAdd(&sums[DMv + c], s2);
}
__global__ void bn_params_k(const float* __restrict__ sums,
                            const float* __restrict__ bn_g, const float* __restrict__ bn_b,
                            float* __restrict__ scsh, int Nn) {
  int c = threadIdx.x;
  float mu  = sums[c] / (float)Nn;
  float var = sums[DMv + c] / (float)Nn - mu*mu;
  float rs  = rsqrtf(var + 1e-5f);
  float sc  = bn_g[c] * rs;
  scsh[c] = sc;
  scsh[DMv + c] = bn_b[c] - mu*sc;
}
__global__ void bn_apply_k(const unsigned short* __restrict__ hbf, const float* __restrict__ scsh,
                           float* __restrict__ out) {
  int c = threadIdx.x; int n = blockIdx.x;
  size_t i = (size_t)n*DMv + c;
  out[i] = fmaf(bf2f(hbf[i]), scsh[c], scsh[DMv + c]);
}

extern "C" void kernel_launch(void* const* d_in, const int* in_sizes, int n_in,
                              void* d_out, int out_size, void* d_ws, size_t ws_size,
                              hipStream_t stream) {
  const int Nn   = in_sizes[0];
  const int Ecnt = in_sizes[2];
  const int*   x         = (const int*)d_in[0];
  const int*   eindex    = (const int*)d_in[1];
  const int*   srcs      = eindex;
  const int*   tgts      = eindex + Ecnt;
  const float* edge_attr = (const float*)d_in[2];
  const float* lut       = (const float*)d_in[3];
  const float* We0       = (const float*)d_in[4];
  const float* be0       = (const float*)d_in[5];
  const float* Wl        = (const float*)d_in[6];
  const float* bl_       = (const float*)d_in[7];
  const float* Wr        = (const float*)d_in[8];
  const float* br_       = (const float*)d_in[9];
  const float* We        = (const float*)d_in[10];
  const float* att       = (const float*)d_in[11];
  const float* Wres      = (const float*)d_in[12];
  const float* bias_g    = (const float*)d_in[13];
  const float* ln_g      = (const float*)d_in[14];
  const float* ln_b      = (const float*)d_in[15];
  const float* bn_g      = (const float*)d_in[16];
  const float* bn_b      = (const float*)d_in[17];

  char* ws = (char*)d_ws;
  size_t off = 0;
  auto alloc = [&](size_t b) { size_t o = off; off += (b + 255) & ~(size_t)255; return o; };
  unsigned short* hbf   = (unsigned short*)(ws + alloc((size_t)Nn*DMv*2));
  unsigned* xlh   = (unsigned*)(ws + alloc((size_t)Nn*192*4));
  unsigned* xrh   = (unsigned*)(ws + alloc((size_t)Nn*192*4));
  unsigned* hresh = (unsigned*)(ws + alloc((size_t)Nn*192*4));
  unsigned* mbpk = (unsigned*)(ws + alloc((size_t)Nn*24*4));
  uint4* bas8  = (uint4*)(ws + alloc((size_t)Ecnt*16));
  int* ofs     = (int*)(ws + alloc((size_t)Ecnt*4));
  uint4* bas8c = (uint4*)(ws + alloc((size_t)Ecnt*16));
  int* ofsc    = (int*)(ws + alloc((size_t)Ecnt*4));
  int* srcc    = (int*)(ws + alloc((size_t)Ecnt*4));
  float* W2    = (float*)(ws + alloc((size_t)2*48*DMv*4));
  unsigned* W2P = (unsigned*)(ws + alloc((size_t)2*24*DMv*4));
  float* bias2 = (float*)(ws + alloc((size_t)2*DMv*4));
  unsigned short* WcatT = (unsigned short*)(ws + alloc((size_t)2*1152*DMv*2));
  int* rowptr  = (int*)(ws + alloc((size_t)(Nn+1)*4));
  int* cnt     = (int*)(ws + alloc((size_t)Nn*4));
  int* fillA   = (int*)(ws + alloc((size_t)Nn*4));
  int* perm    = (int*)(ws + alloc((size_t)Nn*4));
  int* hist    = (int*)(ws + alloc(2048));
  int* binofs  = (int*)(ws + alloc(2048));
  int* fillB   = (int*)(ws + alloc(2048));
  int* bsum    = (int*)(ws + alloc(1024));
  int* bsumx   = (int*)(ws + alloc(1024));
  float* bnsum = (float*)(ws + alloc(2*DMv*4));
  float* scsh  = (float*)(ws + alloc(2*DMv*4));

  embed_k<<<Nn, DMv, 0, stream>>>(x, lut, hbf, cnt);
  w2_k<<<dim3(49, 2), DMv, 0, stream>>>(We0, be0, We, W2, bias2);
  w2p_k<<<dim3(24, 2), DMv, 0, stream>>>(W2, W2P);
  wcat_k<<<dim3(18, 6, 2), 256, 0, stream>>>(Wl, Wr, Wres, WcatT);
  bas8_k<<<(Ecnt+255)/256, 256, 0, stream>>>(edge_attr, bas8, ofs, Ecnt);
  count_k<<<(Ecnt+255)/256, 256, 0, stream>>>(tgts, cnt, fillA, hist, fillB, Ecnt, Nn);
  int nblk = (Nn + 255)/256;
  dhist_k<<<nblk, 256, 0, stream>>>(cnt, hist, Nn);
  dscan_k<<<1, 512, 0, stream>>>(hist, binofs);
  dfill_k<<<nblk, 256, 0, stream>>>(cnt, binofs, fillB, perm, Nn);
  scan1_k<<<nblk, 256, 0, stream>>>(cnt, rowptr, bsum, Nn);
  scan2_k<<<1, 256, 0, stream>>>(bsum, bsumx, nblk);
  scan3_k<<<nblk, 256, 0, stream>>>(rowptr, bsumx, Nn, Ecnt);
  fill_k<<<(Ecnt+255)/256, 256, 0, stream>>>(srcs, tgts, rowptr, fillA,
                                             bas8, ofs, srcc, bas8c, ofsc, Ecnt);
  mb_k<<<(Nn+3)/4, 256, 0, stream>>>(bas8c, ofsc, rowptr, mbpk, bnsum, Nn);

  int mt = (Nn + 127)/128;
  for (int l = 0; l < 2; ++l) {
    mfma_cat_k<<<9*mt, 256, 0, stream>>>(
        hbf, WcatT + (size_t)l*1152*DMv,
        bl_ + (size_t)l*DMv, br_ + (size_t)l*DMv, bias_g + (size_t)l*DMv,
        xlh, xrh, hresh, Nn);
    fused_agg_k<<<(Nn+3)/4, 256, 0, stream>>>(
        xlh, xrh, hresh, bas8c, ofsc, srcc, rowptr, mbpk, perm,
        W2P + (size_t)l*24*DMv, bias2 + (size_t)l*DMv, att + (size_t)l*DMv,
        ln_g + (size_t)l*DMv, ln_b + (size_t)l*DMv, hbf, Nn);
  }
  bn_reduce_k<<<200, DMv, 0, stream>>>(hbf, bnsum, Nn);
  bn_params_k<<<1, DMv, 0, stream>>>(bnsum, bn_g, bn_b, scsh, Nn);
  bn_apply_k<<<Nn, DMv, 0, stream>>>(hbf, scsh, (float*)d_out);
}

// Round 32
// 600.433 us; speedup vs baseline: 1.0136x; 1.0136x over previous
//
#include <hip/hip_runtime.h>
#include <hip/hip_fp16.h>

#define DMv 384
#define DEv 64

typedef __attribute__((ext_vector_type(8))) __bf16 bf16x8;
typedef __attribute__((ext_vector_type(4))) float f32x4;
typedef _Float16 hf16x2 __attribute__((ext_vector_type(2)));

// ---------- bf16 helpers (raw ushort storage) ----------
__device__ __forceinline__ float bf_lo(unsigned u){ return __uint_as_float(u << 16); }
__device__ __forceinline__ float bf_hi(unsigned u){ return __uint_as_float(u & 0xffff0000u); }
__device__ __forceinline__ unsigned short f2bf(float f){
  unsigned u = __float_as_uint(f);
  unsigned r = (u + 0x7fffu + ((u >> 16) & 1u)) >> 16;
  return (unsigned short)r;
}
__device__ __forceinline__ float bf2f(unsigned short s){ return __uint_as_float(((unsigned)s) << 16); }

// ---------- f16 helpers ----------
__device__ __forceinline__ unsigned packh2(float a, float b){
  unsigned short ha = __half_as_ushort(__float2half(a));
  unsigned short hb = __half_as_ushort(__float2half(b));
  return (unsigned)ha | ((unsigned)hb << 16);
}
__device__ __forceinline__ float h_lo(unsigned u){ return __half2float(__ushort_as_half((unsigned short)(u & 0xffffu))); }
__device__ __forceinline__ float h_hi(unsigned u){ return __half2float(__ushort_as_half((unsigned short)(u >> 16))); }
__device__ __forceinline__ hf16x2 u2h(unsigned u){ union { unsigned u; hf16x2 h; } x; x.u = u; return x.h; }
// dot2: c += a.x*b.x + a.y*b.y  (v_dot2_f32_f16)
__device__ __forceinline__ float dot2(unsigned a, unsigned b, float c){
  return __builtin_amdgcn_fdot2(u2h(a), u2h(b), c, false);
}

// column permutation for W2P: lane l owns cols 6l..6l+5; col-pair cp=3l+m stored at l+64m
__device__ __forceinline__ int phi_col(int c){
  int cp = c >> 1, l = cp / 3, m = cp - 3*l;
  return ((l + (m << 6)) << 1) | (c & 1);
}

// ---------- atom embedding: hbf = bf16(lut[x] * sqrt(384)); also zero cnt ----------
__global__ void embed_k(const int* __restrict__ x, const float* __restrict__ lut,
                        unsigned short* __restrict__ hbf, int* __restrict__ cnt) {
  int n = blockIdx.x, c = threadIdx.x;
  if (c == 0) cnt[n] = 0;
  hbf[(size_t)n*DMv + c] = f2bf(lut[(size_t)x[n]*DMv + c] * 19.595917942265423f);
}

// ---------- W2 = We0 @ We  (f32 [2][48][384], rows 41..47 zero), bias2 = be0 @ We ----------
__global__ void w2_k(const float* __restrict__ We0, const float* __restrict__ be0,
                     const float* __restrict__ We, float* __restrict__ W2,
                     float* __restrict__ bias2) {
  int k = blockIdx.x;         // 0..48
  int l = blockIdx.y;
  int j = threadIdx.x;        // 0..383
  const float* Wel = We + (size_t)l*DEv*DMv;
  if (k == 48) {
    float s = 0.f;
    for (int c = 0; c < DEv; ++c) s = fmaf(be0[c], Wel[c*DMv + j], s);
    bias2[l*DMv + j] = s;
    return;
  }
  float s = 0.f;
  if (k < 41) {
    for (int c = 0; c < DEv; ++c) s = fmaf(We0[k*DEv + c], Wel[c*DMv + j], s);
  }
  W2[((size_t)l*48 + k)*DMv + j] = s;
}

// ---------- W2P: f16 row-pair packed, col-permuted  [2][24][384] uints ----------
__global__ void w2p_k(const float* __restrict__ W2, unsigned* __restrict__ W2P) {
  int p = blockIdx.x;         // 0..23 (row pair)
  int l = blockIdx.y;
  int c = threadIdx.x;        // 0..383
  const float* base = W2 + (size_t)l*48*DMv;
  float a = base[(2*p)*DMv + c];
  float b = base[(2*p+1)*DMv + c];
  W2P[((size_t)l*24 + p)*DMv + phi_col(c)] = packh2(a, b);
}

// ---------- WcatT bf16 [2][1152][384]: rows = output col (Wl|Wr|Wres), contiguous K ----------
__global__ void wcat_k(const float* __restrict__ Wl, const float* __restrict__ Wr,
                       const float* __restrict__ Wres, unsigned short* __restrict__ WcatT) {
  int n = blockIdx.x;   // 0..1151
  int l = blockIdx.y;
  int k = threadIdx.x;  // 0..383
  const float* src;
  int nn;
  if (n < 384)      { src = Wl   + (size_t)l*DMv*DMv; nn = n; }
  else if (n < 768) { src = Wr   + (size_t)l*DMv*DMv; nn = n - 384; }
  else              { src = Wres + (size_t)l*DMv*DMv; nn = n - 768; }
  WcatT[((size_t)l*1152 + n)*DMv + k] = f2bf(src[(size_t)k*DMv + nn]);
}

// ---------- per-edge 8-value gaussian basis window (start mult of 4), f16-pair packed ----------
__global__ void bas8_k(const float* __restrict__ edge_attr,
                       uint4* __restrict__ bas8, int* __restrict__ ofs, int Ecnt) {
  int e = blockIdx.x*256 + threadIdx.x;
  if (e >= Ecnt) return;
  float d = edge_attr[e];
  int kc = (int)(d*5.0f + 0.5f);
  int s = (kc - 2) & ~3;
  if (s < 0) s = 0;
  float v[8];
  #pragma unroll
  for (int i = 0; i < 8; ++i) {
    float df = (d - 0.2f*(float)(s+i)) * 5.0f;
    v[i] = __expf(-(df*df)) * (1.0f/1.12f);
  }
  uint4 u;
  u.x = packh2(v[0], v[1]);
  u.y = packh2(v[2], v[3]);
  u.z = packh2(v[4], v[5]);
  u.w = packh2(v[6], v[7]);
  bas8[e] = u;
  ofs[e] = s;
}

// ---------- CSR build (count also zeroes fillA + sort bins) ----------
__global__ void count_k(const int* __restrict__ tgt, int* __restrict__ cnt,
                        int* __restrict__ fillA, int* __restrict__ hist,
                        int* __restrict__ fillB, int Ecnt, int Nn) {
  int e = blockIdx.x*256 + threadIdx.x;
  if (e < Nn) fillA[e] = 0;
  if (e < 512) { hist[e] = 0; fillB[e] = 0; }
  if (e < Ecnt) atomicAdd(&cnt[tgt[e]], 1);
}
// degree histogram: LDS-aggregated (hot bins hit LDS atomics, not global)
__global__ void dhist_k(const int* __restrict__ cnt, int* __restrict__ hist, int Nn) {
  __shared__ int lh[512];
  int tid = threadIdx.x;
  lh[tid] = 0; lh[tid + 256] = 0;
  __syncthreads();
  int t = blockIdx.x*256 + tid;
  if (t < Nn) { int b = cnt[t]; if (b > 511) b = 511; atomicAdd(&lh[b], 1); }
  __syncthreads();
  int v0 = lh[tid], v1 = lh[tid + 256];
  if (v0) atomicAdd(&hist[tid], v0);
  if (v1) atomicAdd(&hist[tid + 256], v1);
}
// descending-degree exclusive bin offsets (single block, 512 threads)
__global__ void dscan_k(const int* __restrict__ hist, int* __restrict__ binofs) {
  __shared__ int tmp[512];
  int tid = threadIdx.x;
  int v = hist[511 - tid];
  tmp[tid] = v; __syncthreads();
  for (int off = 1; off < 512; off <<= 1) {
    int xv = (tid >= off) ? tmp[tid-off] : 0;
    __syncthreads();
    tmp[tid] += xv;
    __syncthreads();
  }
  binofs[511 - tid] = tmp[tid] - v;
}
// scatter nodes into perm, largest degree first: LDS local rank + per-block chunk claim
__global__ void dfill_k(const int* __restrict__ cnt, const int* __restrict__ binofs,
                        int* __restrict__ fillB, int* __restrict__ perm, int Nn) {
  __shared__ int lh[512];     // per-block bin counts (then reused as ranks)
  __shared__ int lbase[512];  // per-block global chunk base per bin
  int tid = threadIdx.x;
  lh[tid] = 0; lh[tid + 256] = 0;
  __syncthreads();
  int t = blockIdx.x*256 + tid;
  int b = -1, lr = 0;
  if (t < Nn) {
    b = cnt[t]; if (b > 511) b = 511;
    lr = atomicAdd(&lh[b], 1);          // local rank within (block, bin)
  }
  __syncthreads();
  int c0 = lh[tid], c1 = lh[tid + 256];
  if (c0) lbase[tid]       = atomicAdd(&fillB[tid], c0);
  if (c1) lbase[tid + 256] = atomicAdd(&fillB[tid + 256], c1);
  __syncthreads();
  if (b >= 0) perm[binofs[b] + lbase[b] + lr] = t;
}
__global__ void scan1_k(const int* __restrict__ cnt, int* __restrict__ rowptr,
                        int* __restrict__ bsum, int n) {
  __shared__ int tmp[256];
  int tid = threadIdx.x, i = blockIdx.x*256 + tid;
  int v = (i < n) ? cnt[i] : 0;
  tmp[tid] = v; __syncthreads();
  for (int off = 1; off < 256; off <<= 1) {
    int xv = (tid >= off) ? tmp[tid-off] : 0;
    __syncthreads();
    tmp[tid] += xv;
    __syncthreads();
  }
  if (i < n) rowptr[i] = tmp[tid] - v;
  if (tid == 255) bsum[blockIdx.x] = tmp[255];
}
__global__ void scan2_k(const int* __restrict__ bsum, int* __restrict__ bsumx, int nb) {
  __shared__ int tmp[256];
  int tid = threadIdx.x;
  int v = (tid < nb) ? bsum[tid] : 0;
  tmp[tid] = v; __syncthreads();
  for (int off = 1; off < 256; off <<= 1) {
    int xv = (tid >= off) ? tmp[tid-off] : 0;
    __syncthreads();
    tmp[tid] += xv;
    __syncthreads();
  }
  bsumx[tid] = tmp[tid] - v;
}
__global__ void scan3_k(int* __restrict__ rowptr, const int* __restrict__ bsumx,
                        int n, int total) {
  int i = blockIdx.x*256 + threadIdx.x;
  if (i < n) rowptr[i] += bsumx[blockIdx.x];
  if (i == 0) rowptr[n] = total;
}
// fill CSR slots with edge records (CSR-ordered copies for streaming access)
__global__ void fill_k(const int* __restrict__ srcs, const int* __restrict__ tgt,
                       const int* __restrict__ rowptr, int* __restrict__ fill,
                       const uint4* __restrict__ bas8, const int* __restrict__ ofs,
                       int* __restrict__ srcc,
                       uint4* __restrict__ bas8c, int* __restrict__ ofsc, int Ecnt) {
  int e = blockIdx.x*256 + threadIdx.x;
  if (e >= Ecnt) return;
  int t = tgt[e];
  int pos = rowptr[t] + atomicAdd(&fill[t], 1);
  srcc[pos] = srcs[e];
  ofsc[pos] = ofs[e];
  bas8c[pos] = bas8[e];
}

// ---------- per-node mean basis: mbpk[N][24] f16-pair packed uints; also zero bnsum ----------
__global__ void mb_k(const uint4* __restrict__ bas8c, const int* __restrict__ ofsc,
                     const int* __restrict__ rowptr,
                     unsigned* __restrict__ mbpk, float* __restrict__ bnsum, int Nn) {
  __shared__ float mbS[4][48];
  int tid = threadIdx.x, lane = tid & 63, wv = tid >> 6;
  int gid = blockIdx.x*256 + tid;
  if (gid < 2*DMv) bnsum[gid] = 0.f;
  int t = blockIdx.x*4 + wv;
  if (t >= Nn) return;
  if (lane < 48) mbS[wv][lane] = 0.f;
  asm volatile("s_waitcnt lgkmcnt(0)" ::: "memory");
  int rp = rowptr[t], deg = rowptr[t+1] - rp;
  for (int base = 0; base < deg; base += 64) {
    int i = base + lane;
    if (i < deg) {
      uint4 bu = bas8c[rp + i];
      int s = ofsc[rp + i];
      atomicAdd(&mbS[wv][s+0], h_lo(bu.x));
      atomicAdd(&mbS[wv][s+1], h_hi(bu.x));
      atomicAdd(&mbS[wv][s+2], h_lo(bu.y));
      atomicAdd(&mbS[wv][s+3], h_hi(bu.y));
      atomicAdd(&mbS[wv][s+4], h_lo(bu.z));
      atomicAdd(&mbS[wv][s+5], h_hi(bu.z));
      atomicAdd(&mbS[wv][s+6], h_lo(bu.w));
      atomicAdd(&mbS[wv][s+7], h_hi(bu.w));
    }
  }
  asm volatile("s_waitcnt lgkmcnt(0)" ::: "memory");
  if (lane < 24) {
    float inv = (deg > 0) ? 1.0f / (float)deg : 0.f;
    float a = (2*lane   < 44) ? mbS[wv][2*lane  ] * inv : 0.f;
    float b = (2*lane+1 < 44) ? mbS[wv][2*lane+1] * inv : 0.f;
    mbpk[(size_t)t*24 + lane] = packh2(a, b);
  }
}

// ---------- bf16 MFMA GEMM: [M x 384] @ [384 x 1152] -> xlh | xrh | hresh (all f16 packed) ----------
// 1D grid, XCD-bijective swizzle: the 9 N-tile blocks sharing an A-tile stay on one XCD -> A is L2-hit.
__global__ __launch_bounds__(256) void mfma_cat_k(
    const unsigned short* __restrict__ Abf,
    const unsigned short* __restrict__ Bt,
    const float* __restrict__ b0, const float* __restrict__ b1, const float* __restrict__ b2,
    unsigned* __restrict__ C0h, unsigned* __restrict__ C1h, unsigned* __restrict__ C2h, int M) {
  __shared__ __align__(16) char smem[64*132*4];   // 33.8 KB: staging (32KB) / C epilogue
  unsigned short* As = (unsigned short*)smem;
  unsigned short* Bs = (unsigned short*)(smem + 16384);
  float* Cs = (float*)smem;
  int tid = threadIdx.x;
  int lane = tid & 63, wv = tid >> 6;
  int wr = wv >> 1, wc = wv & 1;
  // bijective XCD chunk swizzle (nwg not necessarily %8==0)
  int nwg = gridDim.x;
  int q = nwg >> 3, r = nwg & 7;
  int xcd = blockIdx.x & 7, j = blockIdx.x >> 3;
  int base = (xcd < r) ? xcd*(q+1) : r*(q+1) + (xcd - r)*q;
  int wg = base + j;
  int bn = (wg % 9) * 128;
  int bm = (wg / 9) * 128;
  int srow = tid >> 3;
  int scol = (tid & 7) * 8;
  f32x4 acc[4][4] = {};
  uint4 av[4], bv[4];
  #pragma unroll
  for (int c = 0; c < 4; ++c) {
    int gr = bm + c*32 + srow; if (gr >= M) gr = M - 1;
    av[c] = *(const uint4*)(Abf + (size_t)gr*DMv + scol);
    bv[c] = *(const uint4*)(Bt + (size_t)(bn + c*32 + srow)*DMv + scol);
  }
  #pragma unroll
  for (int kt = 0; kt < 6; ++kt) {
    __syncthreads();
    #pragma unroll
    for (int c = 0; c < 4; ++c) {
      int r2 = c*32 + srow;
      int byteA = r2*128 + scol*2;
      byteA ^= ((byteA >> 9) & 1) << 5;
      *(uint4*)((char*)As + byteA) = av[c];
      *(uint4*)((char*)Bs + byteA) = bv[c];
    }
    __syncthreads();
    if (kt < 5) {
      int k0 = (kt+1) * 64;
      #pragma unroll
      for (int c = 0; c < 4; ++c) {
        int gr = bm + c*32 + srow; if (gr >= M) gr = M - 1;
        av[c] = *(const uint4*)(Abf + (size_t)gr*DMv + k0 + scol);
        bv[c] = *(const uint4*)(Bt + (size_t)(bn + c*32 + srow)*DMv + k0 + scol);
      }
    }
    #pragma unroll
    for (int ks = 0; ks < 2; ++ks) {
      bf16x8 af[4], bfv[4];
      #pragma unroll
      for (int m = 0; m < 4; ++m) {
        int r2 = wr*64 + m*16 + (lane & 15);
        int byte = r2*128 + ks*64 + ((lane >> 4)*16);
        byte ^= ((byte >> 9) & 1) << 5;
        af[m] = *(const bf16x8*)((const char*)As + byte);
      }
      #pragma unroll
      for (int n = 0; n < 4; ++n) {
        int r2 = wc*64 + n*16 + (lane & 15);
        int byte = r2*128 + ks*64 + ((lane >> 4)*16);
        byte ^= ((byte >> 9) & 1) << 5;
        bfv[n] = *(const bf16x8*)((const char*)Bs + byte);
      }
      #pragma unroll
      for (int m = 0; m < 4; ++m)
        #pragma unroll
        for (int n = 0; n < 4; ++n)
          acc[m][n] = __builtin_amdgcn_mfma_f32_16x16x32_bf16(af[m], bfv[n], acc[m][n], 0, 0, 0);
    }
  }
  int seg = bn / 384;
  const float* bias = (seg == 0) ? b0 : (seg == 1) ? b1 : b2;
  unsigned* C = (seg == 0) ? C0h : (seg == 1) ? C1h : C2h;
  int cbase = bn - seg*384;
  // epilogue: stage 64x128 halves in LDS (pad 132); all segs packed f16 uint2 stores
  #pragma unroll
  for (int half = 0; half < 2; ++half) {
    __syncthreads();
    if (wr == half) {
      #pragma unroll
      for (int m = 0; m < 4; ++m) {
        int rl = m*16 + ((lane >> 4)*4);
        #pragma unroll
        for (int n = 0; n < 4; ++n) {
          int cl = wc*64 + n*16 + (lane & 15);
          #pragma unroll
          for (int q2 = 0; q2 < 4; ++q2)
            Cs[(rl+q2)*132 + cl] = acc[m][n][q2];
        }
      }
    }
    __syncthreads();
    #pragma unroll
    for (int rep = 0; rep < 8; ++rep) {
      int rl = rep*8 + (tid >> 5);
      int c4 = (tid & 31) * 4;
      int gr = bm + half*64 + rl;
      if (gr < M) {
        float4 v = *(const float4*)&Cs[rl*132 + c4];
        float4 bv4 = *(const float4*)(bias + cbase + c4);
        v.x += bv4.x; v.y += bv4.y; v.z += bv4.z; v.w += bv4.w;
        uint2 pk;
        pk.x = packh2(v.x, v.y);
        pk.y = packh2(v.z, v.w);
        *(uint2*)(C + (size_t)gr*192 + ((cbase + c4) >> 1)) = pk;
      }
    }
  }
}

// ---------- fused phase: 1 node/wave via degree-sorted perm (LPT balance) ----------
__global__ __launch_bounds__(256) void fused_agg_k(
    const unsigned* __restrict__ xlh, const unsigned* __restrict__ xrh,
    const unsigned* __restrict__ hresh,
    const uint4* __restrict__ bas8c, const int* __restrict__ ofsc,
    const int* __restrict__ srcc, const int* __restrict__ rowptr,
    const unsigned* __restrict__ mbpk, const int* __restrict__ perm,
    const unsigned* __restrict__ W2Pg, const float* __restrict__ bias2_l,
    const float* __restrict__ att_l,
    const float* __restrict__ ln_g, const float* __restrict__ ln_b,
    unsigned short* __restrict__ hbf, int Nn) {
  __shared__ unsigned W2P[24 * DMv];          // f16-pair packed, col-permuted, 36.9 KB
  int tid = threadIdx.x;
  for (int i = tid; i < 24*DMv; i += 256) W2P[i] = W2Pg[i];
  __syncthreads();
  int lane = tid & 63, wv = tid >> 6;
  int j0 = lane * 6;
  float att_j[6], b2[6], lg[6], lb[6];
  #pragma unroll
  for (int jj = 0; jj < 6; ++jj) {
    att_j[jj] = att_l[j0 + jj];
    b2[jj]    = bias2_l[j0 + jj];
    lg[jj]    = ln_g[j0 + jj];
    lb[jj]    = ln_b[j0 + jj];
  }
  int idx = blockIdx.x*4 + wv;                // 1 node per wave
  if (idx >= Nn) return;
  int t = perm[idx];                          // degree-descending order
  {
    int rp = rowptr[t], deg = rowptr[t+1] - rp;
    const unsigned* yp = xrh + (size_t)t*192 + lane*3;
    unsigned y0 = yp[0], y1 = yp[1], y2 = yp[2];
    float xrr[6] = {h_lo(y0), h_hi(y0), h_lo(y1), h_hi(y1), h_lo(y2), h_hi(y2)};
    float xrb[6];
    #pragma unroll
    for (int jj = 0; jj < 6; ++jj) xrb[jj] = xrr[jj] + b2[jj];
    float S = 0.f;
    float acc[6] = {0.f,0.f,0.f,0.f,0.f,0.f};
    // edge records in registers (lane 0..7), double-buffered
    int r_src = 0, r_ofs = 0; uint4 r_bu = {0,0,0,0};
    if (deg > 0 && lane < 8) {
      int idx2 = lane; if (idx2 >= deg) idx2 = deg - 1;
      int p = rp + idx2;
      r_src = srcc[p]; r_bu = bas8c[p]; r_ofs = ofsc[p];
    }
    for (int base = 0; base < deg; base += 8) {
      int nb = deg - base; if (nb > 8) nb = 8;
      // prefetch next batch records into regs (independent, overlapped)
      int n_src = 0, n_ofs = 0; uint4 n_bu = {0,0,0,0};
      if (base + 8 < deg && lane < 8) {
        int idx2 = base + 8 + lane; if (idx2 >= deg) idx2 = deg - 1;
        int p = rp + idx2;
        n_src = srcc[p]; n_bu = bas8c[p]; n_ofs = ofsc[p];
      }
      // batch-wide gather: 24 independent 4B loads in flight (12B/lane, f16-packed)
      float xls[8][6];
      #pragma unroll
      for (int s = 0; s < 8; ++s) {
        int sr = __shfl(r_src, s);
        const unsigned* xp = xlh + (size_t)sr*192 + lane*3;
        unsigned u0 = xp[0], u1 = xp[1], u2 = xp[2];
        xls[s][0]=h_lo(u0); xls[s][1]=h_hi(u0); xls[s][2]=h_lo(u1);
        xls[s][3]=h_hi(u1); xls[s][4]=h_lo(u2); xls[s][5]=h_hi(u2);
      }
      #pragma unroll
      for (int s = 0; s < 8; ++s) {
        if (s >= nb) break;
        int p0 = __shfl(r_ofs, s) >> 1;       // wave-uniform pair base
        unsigned bq0 = __shfl((int)r_bu.x, s);
        unsigned bq1 = __shfl((int)r_bu.y, s);
        unsigned bq2 = __shfl((int)r_bu.z, s);
        unsigned bq3 = __shfl((int)r_bu.w, s);
        float m6[6];
        #pragma unroll
        for (int jj = 0; jj < 6; ++jj) m6[jj] = xls[s][jj] + xrb[jj];
        const uint2* row0 = (const uint2*)(W2P + (p0 + 0)*DMv);
        const uint2* row1 = (const uint2*)(W2P + (p0 + 1)*DMv);
        const uint2* row2 = (const uint2*)(W2P + (p0 + 2)*DMv);
        const uint2* row3 = (const uint2*)(W2P + (p0 + 3)*DMv);
        #pragma unroll
        for (int m = 0; m < 3; ++m) {
          uint2 w0 = row0[lane + (m << 6)];
          uint2 w1 = row1[lane + (m << 6)];
          uint2 w2 = row2[lane + (m << 6)];
          uint2 w3 = row3[lane + (m << 6)];
          m6[2*m]   = dot2(w0.x, bq0, m6[2*m]);
          m6[2*m+1] = dot2(w0.y, bq0, m6[2*m+1]);
          m6[2*m]   = dot2(w1.x, bq1, m6[2*m]);
          m6[2*m+1] = dot2(w1.y, bq1, m6[2*m+1]);
          m6[2*m]   = dot2(w2.x, bq2, m6[2*m]);
          m6[2*m+1] = dot2(w2.y, bq2, m6[2*m+1]);
          m6[2*m]   = dot2(w3.x, bq3, m6[2*m]);
          m6[2*m+1] = dot2(w3.y, bq3, m6[2*m+1]);
        }
        float part = 0.f;
        #pragma unroll
        for (int jj = 0; jj < 6; ++jj) {
          float vl = (m6[jj] > 0.f) ? m6[jj] : 0.2f*m6[jj];
          part = fmaf(vl, att_j[jj], part);
        }
        part += __shfl_xor(part, 1);
        part += __shfl_xor(part, 2);
        part += __shfl_xor(part, 4);
        float w = __expf(part);               // this lane's head weight for edge s
        S += w;
        #pragma unroll
        for (int jj = 0; jj < 6; ++jj) acc[jj] = fmaf(w, xls[s][jj], acc[jj]);
      }
      r_src = n_src; r_bu = n_bu; r_ofs = n_ofs;
    }
    // self-loop: eproj = mb @ W2 (dense 24 pairs)
    {
      const unsigned* xp = xlh + (size_t)t*192 + lane*3;
      unsigned u0 = xp[0], u1 = xp[1], u2 = xp[2];
      float xlt[6] = {h_lo(u0), h_hi(u0), h_lo(u1), h_hi(u1), h_lo(u2), h_hi(u2)};
      float m6[6];
      #pragma unroll
      for (int jj = 0; jj < 6; ++jj)
        m6[jj] = xlt[jj] + ((deg > 0) ? xrb[jj] : xrr[jj]);
      const uint4* mbp4 = (const uint4*)(mbpk + (size_t)t*24);
      #pragma unroll
      for (int w6 = 0; w6 < 6; ++w6) {
        uint4 bu = mbp4[w6];
        unsigned bq[4] = {bu.x, bu.y, bu.z, bu.w};
        #pragma unroll
        for (int q = 0; q < 4; ++q) {
          const uint2* rowq = (const uint2*)(W2P + (w6*4 + q)*DMv);
          #pragma unroll
          for (int m = 0; m < 3; ++m) {
            uint2 wv2 = rowq[lane + (m << 6)];
            m6[2*m]   = dot2(wv2.x, bq[q], m6[2*m]);
            m6[2*m+1] = dot2(wv2.y, bq[q], m6[2*m+1]);
          }
        }
      }
      float part = 0.f;
      #pragma unroll
      for (int jj = 0; jj < 6; ++jj) {
        float vl = (m6[jj] > 0.f) ? m6[jj] : 0.2f*m6[jj];
        part = fmaf(vl, att_j[jj], part);
      }
      part += __shfl_xor(part, 1);
      part += __shfl_xor(part, 2);
      part += __shfl_xor(part, 4);
      float w = __expf(part);
      S += w;
      #pragma unroll
      for (int jj = 0; jj < 6; ++jj) acc[jj] = fmaf(w, xlt[jj], acc[jj]);
    }
    // finalize: /S, residual (f16 hres), LayerNorm, write bf16
    float inv = 1.0f / (S + 1e-16f);
    const unsigned* hq = hresh + (size_t)t*192 + lane*3;
    unsigned hh0 = hq[0], hh1 = hq[1], hh2 = hq[2];
    float hr[6] = {h_lo(hh0), h_hi(hh0), h_lo(hh1), h_hi(hh1), h_lo(hh2), h_hi(hh2)};
    float outv[6]; float s1 = 0.f, s2 = 0.f;
    #pragma unroll
    for (int jj = 0; jj < 6; ++jj) {
      float o = fmaf(acc[jj], inv, hr[jj]);
      outv[jj] = o; s1 += o; s2 += o*o;
    }
    #pragma unroll
    for (int m = 1; m < 64; m <<= 1) {
      s1 += __shfl_xor(s1, m);
      s2 += __shfl_xor(s2, m);
    }
    float mu  = s1 * (1.0f/384.0f);
    float var = s2 * (1.0f/384.0f) - mu*mu;
    float rs  = rsqrtf(var + 1e-5f);
    float o0 = (outv[0]-mu)*rs*lg[0] + lb[0];
    float o1 = (outv[1]-mu)*rs*lg[1] + lb[1];
    float o2 = (outv[2]-mu)*rs*lg[2] + lb[2];
    float o3 = (outv[3]-mu)*rs*lg[3] + lb[3];
    float o4 = (outv[4]-mu)*rs*lg[4] + lb[4];
    float o5 = (outv[5]-mu)*rs*lg[5] + lb[5];
    unsigned* hp = (unsigned*)(hbf + (size_t)t*DMv + j0);
    hp[0] = (unsigned)f2bf(o0) | ((unsigned)f2bf(o1) << 16);
    hp[1] = (unsigned)f2bf(o2) | ((unsigned)f2bf(o3) << 16);
    hp[2] = (unsigned)f2bf(o4) | ((unsigned)f2bf(o5) << 16);
  }
}

// ---------- BatchNorm (training-mode batch stats) on bf16 h ----------
__global__ void bn_reduce_k(const unsigned short* __restrict__ hbf, float* __restrict__ sums, int Nn) {
  int c = threadIdx.x;
  float s = 0.f, s2 = 0.f;
  for (int r = blockIdx.x; r < Nn; r += gridDim.x) {
    float v = bf2f(hbf[(size_t)r*DMv + c]);
    s += v; s2 += v*v;
  }
  atomicAdd(&sums[c], s);
  atomicAdd(&sums[DMv + c], s2);
}
__global__ void bn_params_k(const float* __restrict__ sums,
                            const float* __restrict__ bn_g, const float* __restrict__ bn_b,
                            float* __restrict__ scsh, int Nn) {
  int c = threadIdx.x;
  float mu  = sums[c] / (float)Nn;
  float var = sums[DMv + c] / (float)Nn - mu*mu;
  float rs  = rsqrtf(var + 1e-5f);
  float sc  = bn_g[c] * rs;
  scsh[c] = sc;
  scsh[DMv + c] = bn_b[c] - mu*sc;
}
__global__ void bn_apply_k(const unsigned short* __restrict__ hbf, const float* __restrict__ scsh,
                           float* __restrict__ out) {
  int c = threadIdx.x; int n = blockIdx.x;
  size_t i = (size_t)n*DMv + c;
  out[i] = fmaf(bf2f(hbf[i]), scsh[c], scsh[DMv + c]);
}

extern "C" void kernel_launch(void* const* d_in, const int* in_sizes, int n_in,
                              void* d_out, int out_size, void* d_ws, size_t ws_size,
                              hipStream_t stream) {
  const int Nn   = in_sizes[0];
  const int Ecnt = in_sizes[2];
  const int*   x         = (const int*)d_in[0];
  const int*   eindex    = (const int*)d_in[1];
  const int*   srcs      = eindex;
  const int*   tgts      = eindex + Ecnt;
  const float* edge_attr = (const float*)d_in[2];
  const float* lut       = (const float*)d_in[3];
  const float* We0       = (const float*)d_in[4];
  const float* be0       = (const float*)d_in[5];
  const float* Wl        = (const float*)d_in[6];
  const float* bl_       = (const float*)d_in[7];
  const float* Wr        = (const float*)d_in[8];
  const float* br_       = (const float*)d_in[9];
  const float* We        = (const float*)d_in[10];
  const float* att       = (const float*)d_in[11];
  const float* Wres      = (const float*)d_in[12];
  const float* bias_g    = (const float*)d_in[13];
  const float* ln_g      = (const float*)d_in[14];
  const float* ln_b      = (const float*)d_in[15];
  const float* bn_g      = (const float*)d_in[16];
  const float* bn_b      = (const float*)d_in[17];

  char* ws = (char*)d_ws;
  size_t off = 0;
  auto alloc = [&](size_t b) { size_t o = off; off += (b + 255) & ~(size_t)255; return o; };
  unsigned short* hbf   = (unsigned short*)(ws + alloc((size_t)Nn*DMv*2));
  unsigned* xlh   = (unsigned*)(ws + alloc((size_t)Nn*192*4));
  unsigned* xrh   = (unsigned*)(ws + alloc((size_t)Nn*192*4));
  unsigned* hresh = (unsigned*)(ws + alloc((size_t)Nn*192*4));
  unsigned* mbpk = (unsigned*)(ws + alloc((size_t)Nn*24*4));
  uint4* bas8  = (uint4*)(ws + alloc((size_t)Ecnt*16));
  int* ofs     = (int*)(ws + alloc((size_t)Ecnt*4));
  uint4* bas8c = (uint4*)(ws + alloc((size_t)Ecnt*16));
  int* ofsc    = (int*)(ws + alloc((size_t)Ecnt*4));
  int* srcc    = (int*)(ws + alloc((size_t)Ecnt*4));
  float* W2    = (float*)(ws + alloc((size_t)2*48*DMv*4));
  unsigned* W2P = (unsigned*)(ws + alloc((size_t)2*24*DMv*4));
  float* bias2 = (float*)(ws + alloc((size_t)2*DMv*4));
  unsigned short* WcatT = (unsigned short*)(ws + alloc((size_t)2*1152*DMv*2));
  int* rowptr  = (int*)(ws + alloc((size_t)(Nn+1)*4));
  int* cnt     = (int*)(ws + alloc((size_t)Nn*4));
  int* fillA   = (int*)(ws + alloc((size_t)Nn*4));
  int* perm    = (int*)(ws + alloc((size_t)Nn*4));
  int* hist    = (int*)(ws + alloc(2048));
  int* binofs  = (int*)(ws + alloc(2048));
  int* fillB   = (int*)(ws + alloc(2048));
  int* bsum    = (int*)(ws + alloc(1024));
  int* bsumx   = (int*)(ws + alloc(1024));
  float* bnsum = (float*)(ws + alloc(2*DMv*4));
  float* scsh  = (float*)(ws + alloc(2*DMv*4));

  embed_k<<<Nn, DMv, 0, stream>>>(x, lut, hbf, cnt);
  w2_k<<<dim3(49, 2), DMv, 0, stream>>>(We0, be0, We, W2, bias2);
  w2p_k<<<dim3(24, 2), DMv, 0, stream>>>(W2, W2P);
  wcat_k<<<dim3(1152, 2), DMv, 0, stream>>>(Wl, Wr, Wres, WcatT);
  bas8_k<<<(Ecnt+255)/256, 256, 0, stream>>>(edge_attr, bas8, ofs, Ecnt);
  count_k<<<(Ecnt+255)/256, 256, 0, stream>>>(tgts, cnt, fillA, hist, fillB, Ecnt, Nn);
  int nblk = (Nn + 255)/256;
  dhist_k<<<nblk, 256, 0, stream>>>(cnt, hist, Nn);
  dscan_k<<<1, 512, 0, stream>>>(hist, binofs);
  dfill_k<<<nblk, 256, 0, stream>>>(cnt, binofs, fillB, perm, Nn);
  scan1_k<<<nblk, 256, 0, stream>>>(cnt, rowptr, bsum, Nn);
  scan2_k<<<1, 256, 0, stream>>>(bsum, bsumx, nblk);
  scan3_k<<<nblk, 256, 0, stream>>>(rowptr, bsumx, Nn, Ecnt);
  fill_k<<<(Ecnt+255)/256, 256, 0, stream>>>(srcs, tgts, rowptr, fillA,
                                             bas8, ofs, srcc, bas8c, ofsc, Ecnt);
  mb_k<<<(Nn+3)/4, 256, 0, stream>>>(bas8c, ofsc, rowptr, mbpk, bnsum, Nn);

  int mt = (Nn + 127)/128;
  for (int l = 0; l < 2; ++l) {
    mfma_cat_k<<<9*mt, 256, 0, stream>>>(
        hbf, WcatT + (size_t)l*1152*DMv,
        bl_ + (size_t)l*DMv, br_ + (size_t)l*DMv, bias_g + (size_t)l*DMv,
        xlh, xrh, hresh, Nn);
    fused_agg_k<<<(Nn+3)/4, 256, 0, stream>>>(
        xlh, xrh, hresh, bas8c, ofsc, srcc, rowptr, mbpk, perm,
        W2P + (size_t)l*24*DMv, bias2 + (size_t)l*DMv, att + (size_t)l*DMv,
        ln_g + (size_t)l*DMv, ln_b + (size_t)l*DMv, hbf, Nn);
  }
  bn_reduce_k<<<200, DMv, 0, stream>>>(hbf, bnsum, Nn);
  bn_params_k<<<1, DMv, 0, stream>>>(bnsum, bn_g, bn_b, scsh, Nn);
  bn_apply_k<<<Nn, DMv, 0, stream>>>(hbf, scsh, (float*)d_out);
}